// Round 1
// baseline (1631.246 us; speedup 1.0000x reference)
//
#include <hip/hip_runtime.h>

#define NN 50000
#define NE 400000
#define HD 128
#define ND 64
#define GG 16
#define EPSV 1e-5f

typedef unsigned short u16;
typedef unsigned int   u32;

__device__ __forceinline__ float us2f(u16 u) { return __uint_as_float(((u32)u) << 16); }
__device__ __forceinline__ u16 f2us(float f) {
    u32 u = __float_as_uint(f);
    u += 0x7fffu + ((u >> 16) & 1u);   // RNE
    return (u16)(u >> 16);
}
__device__ __forceinline__ float sigmoidf_(float x) { return 1.f / (1.f + __expf(-x)); }

// ---------------------------------------------------------------------------
// K1: fq/fr/fu/fv = features @ {Wq,Wr,Wu,Wv} + b   (bf16 out)
// block = 256 thr (4 waves), 32 rows/block, 8 rows/wave, 2 cols/lane
// ---------------------------------------------------------------------------
__global__ __launch_bounds__(256) void proj4_kernel(
    const float* __restrict__ feat,
    const float* __restrict__ Wq, const float* __restrict__ bq,
    const float* __restrict__ Wr, const float* __restrict__ br,
    const float* __restrict__ Wu, const float* __restrict__ bu,
    const float* __restrict__ Wv, const float* __restrict__ bv,
    u16* __restrict__ fq, u16* __restrict__ fr,
    u16* __restrict__ fu, u16* __restrict__ fv)
{
    __shared__ float xs[32][HD];
    const int t = threadIdx.x;
    const int gbase = blockIdx.x * 32;
    #pragma unroll
    for (int i = 0; i < 8; ++i) {
        int idx2 = t + i * 256;          // float2 index, 0..2047
        int row = idx2 >> 6;
        int c2 = (idx2 & 63) * 2;
        float2 v = make_float2(0.f, 0.f);
        int grow = gbase + row;
        if (grow < NN) v = *reinterpret_cast<const float2*>(&feat[(size_t)grow * HD + c2]);
        xs[row][c2] = v.x; xs[row][c2 + 1] = v.y;
    }
    __syncthreads();
    const int w = t >> 6, lane = t & 63;
    const int c0 = lane * 2, r0 = w * 8;
    const float* Ws[4] = {Wq, Wr, Wu, Wv};
    const float* Bs[4] = {bq, br, bu, bv};
    u16* Os[4] = {fq, fr, fu, fv};
    #pragma unroll
    for (int m = 0; m < 4; ++m) {
        const float* W = Ws[m];
        float acc[8][2];
        #pragma unroll
        for (int r = 0; r < 8; ++r) { acc[r][0] = 0.f; acc[r][1] = 0.f; }
        for (int k = 0; k < HD; k += 2) {
            float2 w0 = *reinterpret_cast<const float2*>(&W[k * HD + c0]);
            float2 w1 = *reinterpret_cast<const float2*>(&W[(k + 1) * HD + c0]);
            #pragma unroll
            for (int r = 0; r < 8; ++r) {
                float2 xv = *reinterpret_cast<const float2*>(&xs[r0 + r][k]);
                acc[r][0] = fmaf(xv.x, w0.x, fmaf(xv.y, w1.x, acc[r][0]));
                acc[r][1] = fmaf(xv.x, w0.y, fmaf(xv.y, w1.y, acc[r][1]));
            }
        }
        float2 b2 = *reinterpret_cast<const float2*>(&Bs[m][c0]);
        #pragma unroll
        for (int r = 0; r < 8; ++r) {
            int grow = gbase + r0 + r;
            if (grow < NN) {
                u32 o = (u32)f2us(acc[r][0] + b2.x) | ((u32)f2us(acc[r][1] + b2.y) << 16);
                *reinterpret_cast<u32*>(&Os[m][(size_t)grow * HD + c0]) = o;
            }
        }
    }
}

// ---------------------------------------------------------------------------
// K2: nme = noise @ We + be   (f32, written directly into e-output region)
// ---------------------------------------------------------------------------
__global__ __launch_bounds__(256) void nme_kernel(
    const float* __restrict__ noise, const float* __restrict__ We,
    const float* __restrict__ be, float* __restrict__ nme_out)
{
    __shared__ float xs[32][ND];
    const int t = threadIdx.x;
    const int gbase = blockIdx.x * 32;
    #pragma unroll
    for (int i = 0; i < 4; ++i) {
        int idx2 = t + i * 256;          // 0..1023
        int row = idx2 >> 5;
        int c2 = (idx2 & 31) * 2;
        float2 v = *reinterpret_cast<const float2*>(&noise[(size_t)(gbase + row) * ND + c2]);
        xs[row][c2] = v.x; xs[row][c2 + 1] = v.y;
    }
    __syncthreads();
    const int w = t >> 6, lane = t & 63;
    const int c0 = lane * 2, r0 = w * 8;
    float acc[8][2];
    #pragma unroll
    for (int r = 0; r < 8; ++r) { acc[r][0] = 0.f; acc[r][1] = 0.f; }
    for (int k = 0; k < ND; k += 2) {
        float2 w0 = *reinterpret_cast<const float2*>(&We[k * HD + c0]);
        float2 w1 = *reinterpret_cast<const float2*>(&We[(k + 1) * HD + c0]);
        #pragma unroll
        for (int r = 0; r < 8; ++r) {
            float2 xv = *reinterpret_cast<const float2*>(&xs[r0 + r][k]);
            acc[r][0] = fmaf(xv.x, w0.x, fmaf(xv.y, w1.x, acc[r][0]));
            acc[r][1] = fmaf(xv.x, w0.y, fmaf(xv.y, w1.y, acc[r][1]));
        }
    }
    float2 b2 = *reinterpret_cast<const float2*>(&be[c0]);
    #pragma unroll
    for (int r = 0; r < 8; ++r) {
        int e = gbase + r0 + r;
        *reinterpret_cast<float2*>(&nme_out[(size_t)e * HD + c0]) =
            make_float2(acc[r][0] + b2.x, acc[r][1] + b2.y);
    }
}

// ---------------------------------------------------------------------------
// K3: e_hat = nme@Wp + bp + fq[src] + fr[dst]; gates=sigmoid; aggr atomics
// ---------------------------------------------------------------------------
__global__ __launch_bounds__(256) void ehat_kernel(
    const float* __restrict__ nme, const float* __restrict__ Wp, const float* __restrict__ bp,
    const u16* __restrict__ fq, const u16* __restrict__ fr, const u16* __restrict__ fv,
    const int* __restrict__ srcArr, const int* __restrict__ dstArr,
    u16* __restrict__ ehat, float* aggr)
{
    __shared__ float xs[32][HD];
    const int t = threadIdx.x;
    const int gbase = blockIdx.x * 32;
    #pragma unroll
    for (int i = 0; i < 8; ++i) {
        int idx2 = t + i * 256;
        int row = idx2 >> 6;
        int c2 = (idx2 & 63) * 2;
        float2 v = *reinterpret_cast<const float2*>(&nme[(size_t)(gbase + row) * HD + c2]);
        xs[row][c2] = v.x; xs[row][c2 + 1] = v.y;
    }
    __syncthreads();
    const int w = t >> 6, lane = t & 63;
    const int c0 = lane * 2, r0 = w * 8;
    float acc[8][2];
    #pragma unroll
    for (int r = 0; r < 8; ++r) { acc[r][0] = 0.f; acc[r][1] = 0.f; }
    for (int k = 0; k < HD; k += 2) {
        float2 w0 = *reinterpret_cast<const float2*>(&Wp[k * HD + c0]);
        float2 w1 = *reinterpret_cast<const float2*>(&Wp[(k + 1) * HD + c0]);
        #pragma unroll
        for (int r = 0; r < 8; ++r) {
            float2 xv = *reinterpret_cast<const float2*>(&xs[r0 + r][k]);
            acc[r][0] = fmaf(xv.x, w0.x, fmaf(xv.y, w1.x, acc[r][0]));
            acc[r][1] = fmaf(xv.x, w0.y, fmaf(xv.y, w1.y, acc[r][1]));
        }
    }
    float2 bp2 = *reinterpret_cast<const float2*>(&bp[c0]);
    #pragma unroll
    for (int r = 0; r < 8; ++r) {
        int e = gbase + r0 + r;
        int s = srcArr[e], d = dstArr[e];
        u32 qv = *reinterpret_cast<const u32*>(&fq[(size_t)s * HD + c0]);
        u32 rv = *reinterpret_cast<const u32*>(&fr[(size_t)d * HD + c0]);
        float e0 = acc[r][0] + bp2.x + us2f((u16)qv) + us2f((u16)rv);
        float e1 = acc[r][1] + bp2.y + us2f((u16)(qv >> 16)) + us2f((u16)(rv >> 16));
        *reinterpret_cast<u32*>(&ehat[(size_t)e * HD + c0]) =
            (u32)f2us(e0) | ((u32)f2us(e1) << 16);
        u32 vv = *reinterpret_cast<const u32*>(&fv[(size_t)d * HD + c0]);
        unsafeAtomicAdd(&aggr[(size_t)s * HD + c0],     sigmoidf_(e0) * us2f((u16)vv));
        unsafeAtomicAdd(&aggr[(size_t)s * HD + c0 + 1], sigmoidf_(e1) * us2f((u16)(vv >> 16)));
    }
}

// ---------------------------------------------------------------------------
// K4: per-graph sum/sumsq of x = fu + aggr  (batch sorted -> register accum)
// ---------------------------------------------------------------------------
__global__ __launch_bounds__(256) void hstats_kernel(
    const u16* __restrict__ fu, const float* __restrict__ aggr,
    const int* __restrict__ batch,
    float* sum_h, float* sumsq_h, float* cnt_h)
{
    __shared__ float s1[GG * HD], s2[GG * HD], sc[GG];
    const int t = threadIdx.x;
    for (int i = t; i < GG * HD; i += 256) { s1[i] = 0.f; s2[i] = 0.f; }
    if (t < GG) sc[t] = 0.f;
    __syncthreads();
    const int nb = gridDim.x;
    const int chunk = (NN + nb - 1) / nb;
    const int rstart = blockIdx.x * chunk;
    const int rend = min(NN, rstart + chunk);
    const int c = t & 127, half = t >> 7;
    float a1 = 0.f, a2 = 0.f, ac = 0.f; int curg = -1;
    for (int row = rstart + half; row < rend; row += 2) {
        int g = batch[row];
        if (g != curg) {
            if (curg >= 0) {
                unsafeAtomicAdd(&s1[curg * HD + c], a1);
                unsafeAtomicAdd(&s2[curg * HD + c], a2);
                if (c == 0) unsafeAtomicAdd(&sc[curg], ac);
            }
            curg = g; a1 = a2 = ac = 0.f;
        }
        float x = us2f(fu[(size_t)row * HD + c]) + aggr[(size_t)row * HD + c];
        a1 += x; a2 += x * x; ac += 1.f;
    }
    if (curg >= 0) {
        unsafeAtomicAdd(&s1[curg * HD + c], a1);
        unsafeAtomicAdd(&s2[curg * HD + c], a2);
        if (c == 0) unsafeAtomicAdd(&sc[curg], ac);
    }
    __syncthreads();
    for (int i = t; i < GG * HD; i += 256) {
        if (s1[i] != 0.f) unsafeAtomicAdd(&sum_h[i], s1[i]);
        if (s2[i] != 0.f) unsafeAtomicAdd(&sumsq_h[i], s2[i]);
    }
    if (t < GG && sc[t] != 0.f) unsafeAtomicAdd(&cnt_h[t], sc[t]);
}

// ---------------------------------------------------------------------------
// K5: per-graph sum/sumsq of e_hat with eseg = batch[src]  (unsorted -> LDS atomics)
// ---------------------------------------------------------------------------
__global__ __launch_bounds__(256) void estats_kernel(
    const u16* __restrict__ ehat, const int* __restrict__ srcArr,
    const int* __restrict__ batch,
    float* sum_e, float* sumsq_e, float* cnt_e)
{
    __shared__ float s1[GG * HD], s2[GG * HD], sc[GG];
    const int t = threadIdx.x;
    for (int i = t; i < GG * HD; i += 256) { s1[i] = 0.f; s2[i] = 0.f; }
    if (t < GG) sc[t] = 0.f;
    __syncthreads();
    const int c = t & 127, half = t >> 7;
    for (int row = blockIdx.x * 2 + half; row < NE; row += gridDim.x * 2) {
        int g = batch[srcArr[row]];
        float x = us2f(ehat[(size_t)row * HD + c]);
        unsafeAtomicAdd(&s1[g * HD + c], x);
        unsafeAtomicAdd(&s2[g * HD + c], x * x);
        if (c == 0) unsafeAtomicAdd(&sc[g], 1.f);
    }
    __syncthreads();
    for (int i = t; i < GG * HD; i += 256) {
        if (s1[i] != 0.f) unsafeAtomicAdd(&sum_e[i], s1[i]);
        if (s2[i] != 0.f) unsafeAtomicAdd(&sumsq_e[i], s2[i]);
    }
    if (t < GG && sc[t] != 0.f) unsafeAtomicAdd(&cnt_e[t], sc[t]);
}

// ---------------------------------------------------------------------------
// K6: stats -> (off = mean*ms, istd);  var = E[x^2] - 2*off*mean + off^2
// ---------------------------------------------------------------------------
__global__ __launch_bounds__(256) void finstats_kernel(
    const float* sum_h, const float* sumsq_h, const float* cnt_h,
    const float* sum_e, const float* sumsq_e, const float* cnt_e,
    const float* __restrict__ gnh_ms, const float* __restrict__ gne_ms,
    float* off_h, float* istd_h, float* off_e, float* istd_e)
{
    for (int i = threadIdx.x; i < GG * HD; i += 256) {
        int g = i >> 7, c = i & 127;
        {
            float cnt = fmaxf(cnt_h[g], 1.f);
            float mean = sum_h[i] / cnt;
            float ex2 = sumsq_h[i] / cnt;
            float off = mean * gnh_ms[c];
            float var = ex2 - 2.f * off * mean + off * off;
            off_h[i] = off;
            istd_h[i] = rsqrtf(var + EPSV);
        }
        {
            float cnt = fmaxf(cnt_e[g], 1.f);
            float mean = sum_e[i] / cnt;
            float ex2 = sumsq_e[i] / cnt;
            float off = mean * gne_ms[c];
            float var = ex2 - 2.f * off * mean + off * off;
            off_e[i] = off;
            istd_e[i] = rsqrtf(var + EPSV);
        }
    }
}

// ---------------------------------------------------------------------------
// K7: tproj = relu(time_emb) @ Wt + bt   [16 x 128]
// ---------------------------------------------------------------------------
__global__ __launch_bounds__(256) void tproj_kernel(
    const float* __restrict__ time_emb, const float* __restrict__ Wt,
    const float* __restrict__ bt, float* __restrict__ tproj)
{
    __shared__ float te[GG][HD];
    const int t = threadIdx.x;
    for (int i = t; i < GG * HD; i += 256) te[i >> 7][i & 127] = fmaxf(time_emb[i], 0.f);
    __syncthreads();
    const int c = t & 127, rb = t >> 7;
    float acc[8];
    #pragma unroll
    for (int j = 0; j < 8; ++j) acc[j] = 0.f;
    for (int k = 0; k < HD; ++k) {
        float wv = Wt[k * HD + c];
        #pragma unroll
        for (int j = 0; j < 8; ++j) acc[j] = fmaf(te[rb + 2 * j][k], wv, acc[j]);
    }
    float b = bt[c];
    #pragma unroll
    for (int j = 0; j < 8; ++j) tproj[(rb + 2 * j) * HD + c] = acc[j] + b;
}

// ---------------------------------------------------------------------------
// K8: h = features + relu(graphnorm_h(fu + aggr));  aggr lives in hout (in-place)
// ---------------------------------------------------------------------------
__global__ __launch_bounds__(256) void hfinal_kernel(
    const float* __restrict__ feat, const u16* __restrict__ fu,
    const int* __restrict__ batch,
    const float* __restrict__ off_h, const float* __restrict__ istd_h,
    const float* __restrict__ gnh_w, const float* __restrict__ gnh_b,
    float* hout_aggr)
{
    int i = blockIdx.x * 256 + threadIdx.x;
    size_t base = (size_t)i * 4;
    if (base >= (size_t)NN * HD) return;
    int row = (int)(base >> 7), c0 = (int)(base & 127);
    int g = batch[row];
    float4 fe = *reinterpret_cast<const float4*>(&feat[base]);
    float4 ag = *reinterpret_cast<const float4*>(&hout_aggr[base]);
    uint2 fv2 = *reinterpret_cast<const uint2*>(&fu[base]);
    float xv[4] = { us2f((u16)fv2.x) + ag.x, us2f((u16)(fv2.x >> 16)) + ag.y,
                    us2f((u16)fv2.y) + ag.z, us2f((u16)(fv2.y >> 16)) + ag.w };
    float4 ou;
    float* op = &ou.x;
    const float* fp = &fe.x;
    #pragma unroll
    for (int j = 0; j < 4; ++j) {
        int idx = g * HD + c0 + j;
        float out = xv[j] - off_h[idx];
        float v = gnh_w[c0 + j] * out * istd_h[idx] + gnh_b[c0 + j];
        op[j] = fp[j] + fmaxf(v, 0.f);
    }
    *reinterpret_cast<float4*>(&hout_aggr[base]) = ou;
}

// ---------------------------------------------------------------------------
// K9: e = nme + silu(LN(relu(graphnorm_e(e_hat)) + tproj[eseg])) @ Wo + bo
//     nme (f32) already resides in eout; read it, write final e in place.
// ---------------------------------------------------------------------------
__global__ __launch_bounds__(256) void efinal_kernel(
    const u16* __restrict__ ehat, const int* __restrict__ srcArr,
    const int* __restrict__ batch,
    const float* __restrict__ off_e, const float* __restrict__ istd_e,
    const float* __restrict__ gne_w, const float* __restrict__ gne_b,
    const float* __restrict__ tproj,
    const float* __restrict__ ln_w, const float* __restrict__ ln_b,
    const float* __restrict__ Wo, const float* __restrict__ bo,
    float* eout)
{
    __shared__ float ss[32][HD];
    const int t = threadIdx.x;
    const int gbase = blockIdx.x * 32;
    const int w = t >> 6, lane = t & 63;
    const int c0 = lane * 2, r0 = w * 8;
    float2 gw = *reinterpret_cast<const float2*>(&gne_w[c0]);
    float2 gb = *reinterpret_cast<const float2*>(&gne_b[c0]);
    float2 lw = *reinterpret_cast<const float2*>(&ln_w[c0]);
    float2 lb = *reinterpret_cast<const float2*>(&ln_b[c0]);
    for (int r = 0; r < 8; ++r) {
        int e = gbase + r0 + r;
        int g = batch[srcArr[e]];
        u32 ev = *reinterpret_cast<const u32*>(&ehat[(size_t)e * HD + c0]);
        float2 ofe = *reinterpret_cast<const float2*>(&off_e[g * HD + c0]);
        float2 ise = *reinterpret_cast<const float2*>(&istd_e[g * HD + c0]);
        float2 tp  = *reinterpret_cast<const float2*>(&tproj[g * HD + c0]);
        float v0 = gw.x * (us2f((u16)ev) - ofe.x) * ise.x + gb.x;
        float v1 = gw.y * (us2f((u16)(ev >> 16)) - ofe.y) * ise.y + gb.y;
        v0 = fmaxf(v0, 0.f) + tp.x;
        v1 = fmaxf(v1, 0.f) + tp.y;
        // rowwise LayerNorm across 128 cols (2 per lane)
        float sum = v0 + v1;
        #pragma unroll
        for (int off = 32; off > 0; off >>= 1) sum += __shfl_xor(sum, off, 64);
        float mu = sum * (1.f / 128.f);
        float d0 = v0 - mu, d1 = v1 - mu;
        float sq = d0 * d0 + d1 * d1;
        #pragma unroll
        for (int off = 32; off > 0; off >>= 1) sq += __shfl_xor(sq, off, 64);
        float rstd = rsqrtf(sq * (1.f / 128.f) + EPSV);
        float l0 = d0 * rstd * lw.x + lb.x;
        float l1 = d1 * rstd * lw.y + lb.y;
        *reinterpret_cast<float2*>(&ss[r0 + r][c0]) =
            make_float2(l0 * sigmoidf_(l0), l1 * sigmoidf_(l1));
    }
    __syncthreads();
    float acc[8][2];
    #pragma unroll
    for (int r = 0; r < 8; ++r) { acc[r][0] = 0.f; acc[r][1] = 0.f; }
    for (int k = 0; k < HD; k += 2) {
        float2 w0 = *reinterpret_cast<const float2*>(&Wo[k * HD + c0]);
        float2 w1 = *reinterpret_cast<const float2*>(&Wo[(k + 1) * HD + c0]);
        #pragma unroll
        for (int r = 0; r < 8; ++r) {
            float2 xv = *reinterpret_cast<const float2*>(&ss[r0 + r][k]);
            acc[r][0] = fmaf(xv.x, w0.x, fmaf(xv.y, w1.x, acc[r][0]));
            acc[r][1] = fmaf(xv.x, w0.y, fmaf(xv.y, w1.y, acc[r][1]));
        }
    }
    float2 bo2 = *reinterpret_cast<const float2*>(&bo[c0]);
    #pragma unroll
    for (int r = 0; r < 8; ++r) {
        int e = gbase + r0 + r;
        float2 nm = *reinterpret_cast<const float2*>(&eout[(size_t)e * HD + c0]);
        *reinterpret_cast<float2*>(&eout[(size_t)e * HD + c0]) =
            make_float2(acc[r][0] + bo2.x + nm.x, acc[r][1] + bo2.y + nm.y);
    }
}

// ---------------------------------------------------------------------------
extern "C" void kernel_launch(void* const* d_in, const int* in_sizes, int n_in,
                              void* d_out, int out_size, void* d_ws, size_t ws_size,
                              hipStream_t stream)
{
    const float* feat     = (const float*)d_in[0];
    const int*   eidx     = (const int*)d_in[1];
    const float* noise    = (const float*)d_in[2];
    const float* time_emb = (const float*)d_in[3];
    const int*   batch    = (const int*)d_in[4];
    const float* We = (const float*)d_in[5],  *be = (const float*)d_in[6];
    const float* Wp = (const float*)d_in[7],  *bp = (const float*)d_in[8];
    const float* Wq = (const float*)d_in[9],  *bq = (const float*)d_in[10];
    const float* Wr = (const float*)d_in[11], *br = (const float*)d_in[12];
    const float* Wu = (const float*)d_in[13], *bu = (const float*)d_in[14];
    const float* Wv = (const float*)d_in[15], *bv = (const float*)d_in[16];
    const float* gnh_w = (const float*)d_in[17], *gnh_b = (const float*)d_in[18], *gnh_ms = (const float*)d_in[19];
    const float* gne_w = (const float*)d_in[20], *gne_b = (const float*)d_in[21], *gne_ms = (const float*)d_in[22];
    const float* Wt = (const float*)d_in[23], *bt = (const float*)d_in[24];
    const float* ln_w = (const float*)d_in[25], *ln_b = (const float*)d_in[26];
    const float* Wo = (const float*)d_in[27], *bo = (const float*)d_in[28];

    const int* srcArr = eidx;
    const int* dstArr = eidx + NE;

    float* hout = (float*)d_out;                    // [N,H] f32 — doubles as aggr
    float* eout = hout + (size_t)NN * HD;           // [E,H] f32 — holds nme then e

    char* ws = (char*)d_ws;
    size_t off = 0;
    auto take = [&](size_t bytes) -> char* {
        char* p = ws + off;
        off = (off + bytes + 255) & ~(size_t)255;
        return p;
    };
    u16* ehat = (u16*)take((size_t)NE * HD * 2);    // 102.4 MB
    u16* fq = (u16*)take((size_t)NN * HD * 2);
    u16* fr = (u16*)take((size_t)NN * HD * 2);
    u16* fu = (u16*)take((size_t)NN * HD * 2);
    u16* fv = (u16*)take((size_t)NN * HD * 2);
    float* stats = (float*)take((size_t)(4 * GG * HD + 2 * GG) * 4);
    float* sum_h   = stats;
    float* sumsq_h = stats + GG * HD;
    float* sum_e   = stats + 2 * GG * HD;
    float* sumsq_e = stats + 3 * GG * HD;
    float* cnt_h   = stats + 4 * GG * HD;
    float* cnt_e   = cnt_h + GG;
    float* tproj  = (float*)take((size_t)GG * HD * 4);
    float* off_h  = (float*)take((size_t)GG * HD * 4);
    float* istd_h = (float*)take((size_t)GG * HD * 4);
    float* off_e  = (float*)take((size_t)GG * HD * 4);
    float* istd_e = (float*)take((size_t)GG * HD * 4);

    // zero the atomic accumulators (hout doubles as aggr) and stats
    hipMemsetAsync(hout, 0, (size_t)NN * HD * 4, stream);
    hipMemsetAsync(stats, 0, (size_t)(4 * GG * HD + 2 * GG) * 4, stream);

    proj4_kernel<<<(NN + 31) / 32, 256, 0, stream>>>(feat, Wq, bq, Wr, br, Wu, bu, Wv, bv,
                                                     fq, fr, fu, fv);
    nme_kernel<<<NE / 32, 256, 0, stream>>>(noise, We, be, eout);
    ehat_kernel<<<NE / 32, 256, 0, stream>>>(eout, Wp, bp, fq, fr, fv, srcArr, dstArr,
                                             ehat, hout);
    hstats_kernel<<<256, 256, 0, stream>>>(fu, hout, batch, sum_h, sumsq_h, cnt_h);
    estats_kernel<<<2048, 256, 0, stream>>>(ehat, srcArr, batch, sum_e, sumsq_e, cnt_e);
    tproj_kernel<<<1, 256, 0, stream>>>(time_emb, Wt, bt, tproj);
    finstats_kernel<<<1, 256, 0, stream>>>(sum_h, sumsq_h, cnt_h, sum_e, sumsq_e, cnt_e,
                                           gnh_ms, gne_ms, off_h, istd_h, off_e, istd_e);
    hfinal_kernel<<<(NN * HD / 4 + 255) / 256, 256, 0, stream>>>(feat, fu, batch, off_h, istd_h,
                                                                 gnh_w, gnh_b, hout);
    efinal_kernel<<<NE / 32, 256, 0, stream>>>(ehat, srcArr, batch, off_e, istd_e,
                                               gne_w, gne_b, tproj, ln_w, ln_b, Wo, bo, eout);
}